// Round 8
// baseline (312.152 us; speedup 1.0000x reference)
//
#include <hip/hip_runtime.h>
#include <math.h>

// TriOut: z[L,L,Z] -> LN -> gated proj to C -> einsum('ilc,jlc->ijc') -> LN(C)
//         -> proj back to Z -> * sigmoid(zn@g_w+g_b)
// L=768, Z=128, C=32.  Output fp32 [L,L,Z].
//
// ws layout (all disjoint, no aliasing):
//   a_t   : bf16 [C][L*L]    ( 37,748,736 B) @ 0          a, c-major
//   zn_g  : bf16 [L*L][Z]    (150,994,944 B) @ 37748736   LN(z) raw (gate made in k3)
//   obuf16: bf16 [C][L*L]    ( 37,748,736 B) @ 188743680  einsum result, c-major
//   afrag : bf16 [16][64][8] ( 16,384 B)     @ 226492416  a/ag weights, frag order
//   gfrag : bf16 [32][64][8] ( 32,768 B)     @ 226508800  g_w frag order
//   ofrag : bf16 [ 8][64][8] (  8,192 B)     @ 226541568  o_w frag order

#define LDIM 768
#define LL   (768 * 768)
#define ZD   128
#define CD   32

typedef __bf16 bf16x8 __attribute__((ext_vector_type(8)));
typedef float  f32x4  __attribute__((ext_vector_type(4)));

__device__ __forceinline__ ushort f2bf(float f) {
    __bf16 h = (__bf16)f;                      // RNE convert
    return __builtin_bit_cast(ushort, h);
}
__device__ __forceinline__ float bf2f(ushort u) {
    return __builtin_bit_cast(float, ((unsigned)u) << 16);
}
// fast sigmoid: v_exp_f32 + v_rcp_f32 (~1 ulp fp32 -- far below bf16 rounding)
__device__ __forceinline__ float sigm(float x) {
    return __builtin_amdgcn_rcpf(1.0f + __expf(-x));
}

// ---------------------------------------------------------------------------
// k0: pack weights into MFMA B-fragment order (frag f, lane l=(fr,hi)):
//   afrag[f=t*4+kk][l] = W_t[(t&1)*16+fr][kk*32+hi*8+j], t: 0,1=a_w 2,3=ag_w
//   gfrag[f=n*4+kk][l] = g_w[n*16+fr][kk*32+hi*8+j]
//   ofrag[f=n     ][l] = o_w[n*16+fr][hi*8+j]            (K=32, single step)
// ---------------------------------------------------------------------------
__global__ __launch_bounds__(256) void k0_frags(
    const float* __restrict__ aw, const float* __restrict__ agw,
    const float* __restrict__ gw, const float* __restrict__ ow,
    ushort* __restrict__ afrag, ushort* __restrict__ gfrag,
    ushort* __restrict__ ofrag)
{
    const int idx = blockIdx.x * 256 + threadIdx.x;   // 3584 total
    if (idx >= 3584) return;
    const int lane = idx & 63;
    const int fr = lane & 15, hi = lane >> 4;
    union { ushort us[8]; uint4 q; } pk;
    if (idx < 1024) {                 // afrag
        const int f = idx >> 6, t = f >> 2, kk = f & 3;
        const float* src = ((t < 2) ? aw : agw) + ((t & 1) * 16 + fr) * ZD + kk * 32 + hi * 8;
        #pragma unroll
        for (int j = 0; j < 8; ++j) pk.us[j] = f2bf(src[j]);
        *(uint4*)&afrag[(size_t)f * 512 + lane * 8] = pk.q;
    } else if (idx < 3072) {          // gfrag
        const int f = (idx - 1024) >> 6, n = f >> 2, kk = f & 3;
        const float* src = gw + (n * 16 + fr) * ZD + kk * 32 + hi * 8;
        #pragma unroll
        for (int j = 0; j < 8; ++j) pk.us[j] = f2bf(src[j]);
        *(uint4*)&gfrag[(size_t)f * 512 + lane * 8] = pk.q;
    } else {                          // ofrag
        const int n = (idx - 3072) >> 6;
        const float* src = ow + (n * 16 + fr) * CD + hi * 8;
        #pragma unroll
        for (int j = 0; j < 8; ++j) pk.us[j] = f2bf(src[j]);
        *(uint4*)&ofrag[(size_t)n * 512 + lane * 8] = pk.q;
    }
}

// ---------------------------------------------------------------------------
// k1 v4: BARRIER-FREE.  2304 blocks x 4 chunks x 64 rows; m-split: wave w owns
// rows w*16..+15 (LN lanes, MFMA rows, zn slice all wave-private).
//   - a/ag B-frags (16) held in registers; zero weight loads in the loop.
//   - LN -> znw (wave-private LDS) -> coalesced zn_g store + 16 MFMA -> a_t.
//   - z for chunk c+1 prefetched into regs during chunk c.
// ---------------------------------------------------------------------------
__global__ __launch_bounds__(256) void k1_ln_proj(
    const float* __restrict__ z, const float* __restrict__ nw, const float* __restrict__ nb,
    const ushort* __restrict__ afrag,
    const float* __restrict__ ab, const float* __restrict__ agb,
    ushort* __restrict__ a_t, ushort* __restrict__ zn_g)
{
    __shared__ ushort znw[4][16][136];

    const int tid = threadIdx.x;
    const int lane = tid & 63, wave = tid >> 6;
    const int fr = lane & 15, hi = lane >> 4;

    // B-frags: 4 tiles (a0,a1,ag0,ag1) x 4 k, held in 64 VGPR
    bf16x8 bfr[4][4];
    {
        const ushort* wl = afrag + (size_t)lane * 8;
        #pragma unroll
        for (int t = 0; t < 4; ++t)
            #pragma unroll
            for (int kk = 0; kk < 4; ++kk)
                bfr[t][kk] = *(const bf16x8*)(wl + (size_t)(t * 4 + kk) * 512);
    }
    const float ab0 = ab[fr], ab1 = ab[16 + fr];
    const float agb0 = agb[fr], agb1 = agb[16 + fr];

    const size_t blockrow = (size_t)blockIdx.x * 256;
    const int lr = lane >> 2, seg = lane & 3;     // LN: 4 lanes/row, 16 rows/wave

    float4 zreg[8];
    {
        const float4* zp = (const float4*)(z + (blockrow + wave * 16 + lr) * ZD + seg * 32);
        #pragma unroll
        for (int q = 0; q < 8; ++q) zreg[q] = zp[q];
    }

    for (int c = 0; c < 4; ++c) {
        const size_t rowc = blockrow + c * 64 + wave * 16;

        // ---- LN from prefetched regs -> znw[wave] bf16 ----
        {
            float v[32];
            #pragma unroll
            for (int q = 0; q < 8; ++q) {
                v[q * 4 + 0] = zreg[q].x; v[q * 4 + 1] = zreg[q].y;
                v[q * 4 + 2] = zreg[q].z; v[q * 4 + 3] = zreg[q].w;
            }
            float s = 0.f, ss = 0.f;
            #pragma unroll
            for (int e = 0; e < 32; ++e) { s += v[e]; ss += v[e] * v[e]; }
            s += __shfl_xor(s, 1); ss += __shfl_xor(ss, 1);
            s += __shfl_xor(s, 2); ss += __shfl_xor(ss, 2);
            const float mu  = s * (1.f / 128.f);
            const float var = ss * (1.f / 128.f) - mu * mu;
            const float rs  = rsqrtf(var + 1e-5f);
            union { ushort u[32]; uint4 q4[4]; } pk;
            #pragma unroll
            for (int e = 0; e < 32; ++e) {
                const int k = seg * 32 + e;
                pk.u[e] = f2bf((v[e] - mu) * rs * nw[k] + nb[k]);
            }
            #pragma unroll
            for (int q = 0; q < 4; ++q)
                *(uint4*)&znw[wave][lr][seg * 32 + q * 8] = pk.q4[q];
        }

        // ---- prefetch next chunk's z ----
        if (c < 3) {
            const float4* zp = (const float4*)(z + (rowc + 64 + lr - wave * 16 + wave * 16) * ZD + seg * 32);
            #pragma unroll
            for (int q = 0; q < 8; ++q) zreg[q] = zp[q];
        }

        // ---- coalesced zn_g copy-out (wave-private LDS -> 256B row runs) ----
        #pragma unroll
        for (int i = 0; i < 4; ++i) {
            const int r = i * 4 + hi;      // hi reused as row-subgroup
            const int c8 = fr * 8;
            *(uint4*)&zn_g[(rowc + r) * ZD + c8] = *(const uint4*)&znw[wave][r][c8];
        }

        // ---- MFMA: 4 tiles x 4 k for this wave's 16 rows ----
        bf16x8 af[4];
        #pragma unroll
        for (int kk = 0; kk < 4; ++kk)
            af[kk] = *(const bf16x8*)&znw[wave][fr][kk * 32 + hi * 8];

        f32x4 acc[4];
        #pragma unroll
        for (int t = 0; t < 4; ++t) acc[t] = (f32x4){0.f, 0.f, 0.f, 0.f};
        #pragma unroll
        for (int kk = 0; kk < 4; ++kk)
            #pragma unroll
            for (int t = 0; t < 4; ++t)
                acc[t] = __builtin_amdgcn_mfma_f32_16x16x32_bf16(af[kk], bfr[t][kk], acc[t], 0, 0, 0);

        // ---- epilogue: a = (a_lin+ab)*sigm(ag_lin+agb) -> a_t c-major ----
        {
            union { ushort u[4]; uint2 d; } pk;
            #pragma unroll
            for (int q = 0; q < 4; ++q)
                pk.u[q] = f2bf((acc[0][q] + ab0) * sigm(acc[2][q] + agb0));
            *(uint2*)&a_t[(size_t)fr * LL + rowc + hi * 4] = pk.d;
            #pragma unroll
            for (int q = 0; q < 4; ++q)
                pk.u[q] = f2bf((acc[1][q] + ab1) * sigm(acc[3][q] + agb1));
            *(uint2*)&a_t[(size_t)(16 + fr) * LL + rowc + hi * 4] = pk.d;
        }
    }
}

// ---------------------------------------------------------------------------
// k2: 32 batched SYMMETRIC GEMMs  O_c = M_c * M_c^T, upper-triangular tiles
// only (78 pairs), mirror-write for off-diagonal.  Output bf16 obuf16.
// Staging via global_load_lds (linear dest = tid*16B).
// ---------------------------------------------------------------------------
__global__ __launch_bounds__(256) void k2_einsum(
    const ushort* __restrict__ a_t, ushort* __restrict__ obuf16)
{
    __shared__ ushort As[2][64][32];
    __shared__ ushort Bs[2][64][32];

    const int tid = threadIdx.x;
    const int c = blockIdx.y;
    int p = blockIdx.x, bi = 0;
    while (p >= 12 - bi) { p -= 12 - bi; ++bi; }
    const int bj = bi + p;
    const int i0 = bi * 64, j0 = bj * 64;
    const ushort* base = a_t + (size_t)c * LL;

    const int srow = tid >> 2, scol = (tid & 3) * 8;
    const ushort* gA = base + (size_t)(i0 + srow) * LDIM + scol;
    const ushort* gB = base + (size_t)(j0 + srow) * LDIM + scol;

    const int wave = tid >> 6, lane = tid & 63;
    const int wi = (wave >> 1) * 32, wj = (wave & 1) * 32;
    const int fr = lane & 15, k8 = (lane >> 4) * 8;

    f32x4 acc[2][2];
    #pragma unroll
    for (int m = 0; m < 2; ++m)
        #pragma unroll
        for (int n = 0; n < 2; ++n)
            acc[m][n] = (f32x4){0.f, 0.f, 0.f, 0.f};

    auto stage = [&](int b, int kc) {
        __builtin_amdgcn_global_load_lds(
            (const uint*)(gA + kc * 32), (uint*)&As[b][srow][scol], 16, 0, 0);
        __builtin_amdgcn_global_load_lds(
            (const uint*)(gB + kc * 32), (uint*)&Bs[b][srow][scol], 16, 0, 0);
    };

    stage(0, 0);
    __syncthreads();
    for (int kc = 0; kc < 24; ++kc) {
        const int cur = kc & 1;
        if (kc + 1 < 24) stage(cur ^ 1, kc + 1);

        bf16x8 av[2], bv[2];
        #pragma unroll
        for (int m = 0; m < 2; ++m)
            av[m] = *(const bf16x8*)&As[cur][wi + m * 16 + fr][k8];
        #pragma unroll
        for (int n = 0; n < 2; ++n)
            bv[n] = *(const bf16x8*)&Bs[cur][wj + n * 16 + fr][k8];

        #pragma unroll
        for (int m = 0; m < 2; ++m)
            #pragma unroll
            for (int n = 0; n < 2; ++n)
                acc[m][n] = __builtin_amdgcn_mfma_f32_16x16x32_bf16(
                    av[m], bv[n], acc[m][n], 0, 0, 0);
        __syncthreads();
    }

    ushort* ob = obuf16 + (size_t)c * LL;
    #pragma unroll
    for (int m = 0; m < 2; ++m)
        #pragma unroll
        for (int n = 0; n < 2; ++n) {
            #pragma unroll
            for (int q = 0; q < 4; ++q) {
                const int row = i0 + wi + m * 16 + (lane >> 4) * 4 + q;
                const int col = j0 + wj + n * 16 + fr;
                ob[(size_t)row * LDIM + col] = f2bf(acc[m][n][q]);
            }
            if (bi != bj) {
                const int mrow = j0 + wj + n * 16 + fr;
                const int mcol = i0 + wi + m * 16 + (lane >> 4) * 4;
                union { ushort u[4]; uint2 d; } pk;
                #pragma unroll
                for (int q = 0; q < 4; ++q) pk.u[q] = f2bf(acc[m][n][q]);
                *(uint2*)&ob[(size_t)mrow * LDIM + mcol] = pk.d;
            }
        }
}

// ---------------------------------------------------------------------------
// k3 v2: per 64 rows: gather obuf16 -> LN(C) -> An (wave-private);
//   stage zn -> Zl (wave-private); o-proj (8 MFMA) + g-proj (32 MFMA) from
//   global frag buffers (L2-hot); gate applied IN REGISTERS;
//   out via wave-private Res transpose, two 64-col halves.  ONE barrier.
// ---------------------------------------------------------------------------
__global__ __launch_bounds__(256) void k3_out(
    const ushort* __restrict__ obuf16, const ushort* __restrict__ zn_g,
    const float* __restrict__ onw, const float* __restrict__ onb,
    const ushort* __restrict__ gfrag, const ushort* __restrict__ ofrag,
    const float* __restrict__ obias, const float* __restrict__ gb,
    float* __restrict__ out)
{
    __shared__ float  Ol[64][33];
    __shared__ ushort An[4][16][36];
    __shared__ ushort Zl[4][16][136];
    __shared__ float  Res[4][16][68];

    const int tid = threadIdx.x;
    const int lane = tid & 63, wave = tid >> 6;
    const int fr = lane & 15, hi = lane >> 4;
    const size_t rowbase = (size_t)blockIdx.x * 64;
    const int wrow = wave * 16;

    // ---- gather obuf16 (c-major, bf16): wave handles 8 channels ----
    #pragma unroll
    for (int cc = 0; cc < 4; ++cc) {
        const int ch = wave * 8 + cc * 2 + (lane >> 5);
        const int r2 = (lane & 31) * 2;
        const uint u = *(const uint*)&obuf16[(size_t)ch * LL + rowbase + r2];
        Ol[r2][ch]     = bf2f((ushort)(u & 0xffff));
        Ol[r2 + 1][ch] = bf2f((ushort)(u >> 16));
    }
    // ---- stage zn rows (wave-private, coalesced 256B runs) ----
    #pragma unroll
    for (int i = 0; i < 4; ++i) {
        const int r = i * 4 + hi;
        *(uint4*)&Zl[wave][r][fr * 8] =
            *(const uint4*)&zn_g[(rowbase + wrow + r) * ZD + fr * 8];
    }
    __syncthreads();   // Ol complete (cross-wave)

    // ---- LN over C=32 -> An[wave] (wave-private rows) ----
    {
        const int r = lane >> 2, seg = lane & 3;
        float v[8];
        #pragma unroll
        for (int e = 0; e < 8; ++e) v[e] = Ol[wrow + r][seg * 8 + e];
        float s = 0.f, ss = 0.f;
        #pragma unroll
        for (int e = 0; e < 8; ++e) { s += v[e]; ss += v[e] * v[e]; }
        s += __shfl_xor(s, 1); ss += __shfl_xor(ss, 1);
        s += __shfl_xor(s, 2); ss += __shfl_xor(ss, 2);
        const float mu  = s * (1.f / 32.f);
        const float var = ss * (1.f / 32.f) - mu * mu;
        const float rs  = rsqrtf(var + 1e-5f);
        union { ushort us[8]; uint4 q; } pk;
        #pragma unroll
        for (int e = 0; e < 8; ++e) {
            const int c = seg * 8 + e;
            pk.us[e] = f2bf((v[e] - mu) * rs * onw[c] + onb[c]);
        }
        *(uint4*)&An[wave][r][seg * 8] = pk.q;
    }

    // ---- MFMA: o-proj (K=32) + g-proj (K=128), frags from global ----
    const bf16x8 afo = *(const bf16x8*)&An[wave][fr][hi * 8];
    bf16x8 afg[4];
    #pragma unroll
    for (int kk = 0; kk < 4; ++kk)
        afg[kk] = *(const bf16x8*)&Zl[wave][fr][kk * 32 + hi * 8];

    const ushort* gl = gfrag + (size_t)lane * 8;
    const ushort* ol = ofrag + (size_t)lane * 8;
    f32x4 po[8], pg[8];
    #pragma unroll
    for (int n = 0; n < 8; ++n) {
        po[n] = __builtin_amdgcn_mfma_f32_16x16x32_bf16(
            afo, *(const bf16x8*)(ol + (size_t)n * 512),
            (f32x4){0.f, 0.f, 0.f, 0.f}, 0, 0, 0);
        pg[n] = (f32x4){0.f, 0.f, 0.f, 0.f};
        #pragma unroll
        for (int kk = 0; kk < 4; ++kk)
            pg[n] = __builtin_amdgcn_mfma_f32_16x16x32_bf16(
                afg[kk], *(const bf16x8*)(gl + (size_t)(n * 4 + kk) * 512),
                pg[n], 0, 0, 0);
    }

    // ---- combine (gate in regs) -> Res transpose -> out, two halves ----
    #pragma unroll
    for (int h = 0; h < 2; ++h) {
        #pragma unroll
        for (int nn = 0; nn < 4; ++nn) {
            const int n = h * 4 + nn;
            const int ch = n * 16 + fr;
            const float obv = obias[ch], gbv = gb[ch];
            #pragma unroll
            for (int q = 0; q < 4; ++q)
                Res[wave][hi * 4 + q][nn * 16 + fr] =
                    (po[n][q] + obv) * sigm(pg[n][q] + gbv);
        }
        #pragma unroll
        for (int i = 0; i < 4; ++i) {
            const int r = i * 4 + hi;
            *(float4*)&out[(rowbase + wrow + r) * ZD + h * 64 + fr * 4] =
                *(const float4*)&Res[wave][r][fr * 4];
        }
    }
}

extern "C" void kernel_launch(void* const* d_in, const int* in_sizes, int n_in,
                              void* d_out, int out_size, void* d_ws, size_t ws_size,
                              hipStream_t stream) {
    (void)in_sizes; (void)n_in; (void)out_size; (void)ws_size;
    const float* z   = (const float*)d_in[0];
    const float* nw  = (const float*)d_in[1];
    const float* nb  = (const float*)d_in[2];
    const float* onw = (const float*)d_in[3];
    const float* onb = (const float*)d_in[4];
    const float* aw  = (const float*)d_in[5];
    const float* ab  = (const float*)d_in[6];
    const float* agw = (const float*)d_in[7];
    const float* agb = (const float*)d_in[8];
    const float* gw  = (const float*)d_in[9];
    const float* gb  = (const float*)d_in[10];
    const float* ow  = (const float*)d_in[11];
    const float* ob  = (const float*)d_in[12];

    char* ws = (char*)d_ws;
    ushort* a_t    = (ushort*)ws;                       // 37,748,736 B
    ushort* zn_g   = (ushort*)(ws + 37748736);          // 150,994,944 B
    ushort* obuf16 = (ushort*)(ws + 188743680);         // 37,748,736 B
    ushort* afrag  = (ushort*)(ws + 226492416);         // 16,384 B
    ushort* gfrag  = (ushort*)(ws + 226508800);         // 32,768 B
    ushort* ofrag  = (ushort*)(ws + 226541568);         // 8,192 B

    k0_frags<<<14, 256, 0, stream>>>(aw, agw, gw, ow, afrag, gfrag, ofrag);
    k1_ln_proj<<<LL / 256, 256, 0, stream>>>(z, nw, nb, afrag, ab, agb,
                                             a_t, zn_g);
    k2_einsum<<<dim3(78, 32), 256, 0, stream>>>(a_t, obuf16);
    k3_out<<<LL / 64, 256, 0, stream>>>(obuf16, zn_g, onw, onb, gfrag, ofrag,
                                        ob, gb, (float*)d_out);
}